// Round 9
// baseline (400.380 us; speedup 1.0000x reference)
//
#include <hip/hip_runtime.h>

typedef unsigned short u16;
typedef unsigned int u32;
typedef unsigned long long u64;
typedef float f32x4 __attribute__((ext_vector_type(4)));
typedef short bf16x8 __attribute__((ext_vector_type(8)));   // 8 bf16 bit-patterns (4 VGPRs)

#define DEV static __device__ __forceinline__

DEV float bf2f(u16 u){ union{float f; u32 i;} x; x.i = ((u32)u) << 16; return x.f; }
DEV u16 f2bf(float f){ union{float f; u32 i;} x; x.f = f; u32 u = x.i;
  return (u16)((u + 0x7fffu + ((u >> 16) & 1u)) >> 16); }           // RNE
DEV u16 f2h(float f){ _Float16 h = (_Float16)f; u16 u; __builtin_memcpy(&u, &h, 2); return u; }
DEV float h2f(u16 u){ _Float16 h; __builtin_memcpy(&h, &u, 2); return (float)h; }
DEV uint4 pack8(const u16* s){ uint4 v;
  v.x = (u32)s[0] | ((u32)s[1]<<16); v.y = (u32)s[2] | ((u32)s[3]<<16);
  v.z = (u32)s[4] | ((u32)s[5]<<16); v.w = (u32)s[6] | ((u32)s[7]<<16); return v; }
DEV f32x4 mfma16(bf16x8 a, bf16x8 b, f32x4 c){
  return __builtin_amdgcn_mfma_f32_16x16x32_bf16(a, b, c, 0, 0, 0);
}
DEV bf16x8 ldfrag(const u16* p){ return *(const bf16x8*)p; }

// agent-scope relaxed atomics (sc0/sc1: MALL-coherent, nothing dirty in XCD L2)
DEV void st_agent(float* p, float v){
  __hip_atomic_store(p, v, __ATOMIC_RELAXED, __HIP_MEMORY_SCOPE_AGENT); }
DEV float ld_agentf(const float* p){
  return __hip_atomic_load(p, __ATOMIC_RELAXED, __HIP_MEMORY_SCOPE_AGENT); }
DEV float2 ld_agent2(const float* p){
  u64 u = __hip_atomic_load((const u64*)p, __ATOMIC_RELAXED, __HIP_MEMORY_SCOPE_AGENT);
  union{u64 u; float2 f;} c; c.u = u; return c.f; }
DEV void st_agent_u32(u32* p, u32 v){
  __hip_atomic_store(p, v, __ATOMIC_RELAXED, __HIP_MEMORY_SCOPE_AGENT); }
DEV u32 ld_agent_u32(const u32* p){
  return __hip_atomic_load(p, __ATOMIC_RELAXED, __HIP_MEMORY_SCOPE_AGENT); }

constexpr float SCL = 144.269504088896341f;    // 100*log2(e) = 1/(eps*ln2), eps=0.01
constexpr float LOG2MU = -9.99998522680257f;   // log2(1/1024 + 1e-8)

// ---------------- workspace layout ----------------
// Packed activation layout AP[ck][row=b*1024+px][32]: elem = (ck*4096+row)*32+c
constexpr size_t MB = 1ull << 20;
constexpr size_t OFF_G    = 0;                 // f16 [4][1024][1024]
constexpr size_t OFF_GT   = 8*MB;              // f16 transpose
constexpr size_t OFF_U    = 16*MB;             // fp32 [4][1024]
constexpr size_t OFF_V    = OFF_U   + (16<<10);
constexpr size_t OFF_BAR  = OFF_V   + (16<<10);// barrier flags u32 [4][64][16] (64B stride)
constexpr size_t OFF_CTR  = OFF_BAR + (16<<10);// bn counters u32[256] (2 used, 64B apart)
constexpr size_t OFF_CNM  = OFF_CTR + (16<<10);
constexpr size_t OFF_CNIS = OFF_CNM + (8<<10);
constexpr size_t OFF_BNS  = OFF_CNIS+ (8<<10);
constexpr size_t OFF_PNP  = OFF_BNS + (4<<10); // pixel-norm partials [2][8][4096] f32 = 256 KB
constexpr size_t OFF_CFH  = 17*MB;             // bf16 [4][1024][512]
constexpr size_t OFF_CFL  = 21*MB;
constexpr size_t OFF_SFH  = 25*MB;
constexpr size_t OFF_SFL  = 29*MB;
constexpr size_t OFF_SNB  = 33*MB;             // bf16 style NCHW [4][512][1024]
constexpr size_t OFF_TN   = 37*MB;             // fp32 t NHWC [4][1024][512]
constexpr size_t OFF_TCP  = 45*MB;             // bf16 packed concat: 32 chunks
constexpr size_t OFF_W1P  = 53*MB;             // frag-order bf16 weights
constexpr size_t OFF_W2P  = OFF_W1P + 9*256*1024*2;
constexpr size_t OFF_W3P  = OFF_W2P + 9*256*256*2;
constexpr size_t OFF_WDP  = OFF_W3P + 9*512*256*2;   // [9][16][512]
// reuse (dead after cgemm / in-sink tgemm):
constexpr size_t OFF_Z1  = 17*MB;              // fp32 partials 2x[4096][256]
constexpr size_t OFF_A1P = 25*MB;              // packed bf16, 8 chunks
constexpr size_t OFF_Z2  = 27*MB;              // fp32 partials 2x[4096][256]
constexpr size_t OFF_A2P = 35*MB;              // packed bf16, 8 chunks
constexpr size_t OFF_T2P = 17*MB;              // packed bf16, 16 chunks (z1 dead)

// ---------------- fused stats + weight pack:
//   chan_stats (0..2047) + pix_part (2048..2303) + zero UV (2304..2335)
//   + zero BN sums (2336..2339) + zero flags (2340..2355) + zero bn ctrs (2356)
//   + pack (2357..3540)
__global__ void stats_k(const float* __restrict__ cf, const float* __restrict__ sf,
                        float* __restrict__ cnm, float* __restrict__ cnis,
                        float* __restrict__ part, float* __restrict__ zUV,
                        float* __restrict__ zBNS, u32* __restrict__ zbar,
                        u32* __restrict__ zctr,
                        const float* __restrict__ w1, const float* __restrict__ w2,
                        const float* __restrict__ w3, const float* __restrict__ wd,
                        u16* __restrict__ w1p, u16* __restrict__ w2p,
                        u16* __restrict__ w3p, u16* __restrict__ wdp){
  int blk = blockIdx.x;
  if (blk < 2048){                              // content channel stats
    int bd = blk;
    float4 v = ((const float4*)(cf + (size_t)bd*1024))[threadIdx.x];
    float s = v.x+v.y+v.z+v.w;
    float q = v.x*v.x+v.y*v.y+v.z*v.z+v.w*v.w;
    #pragma unroll
    for (int m = 32; m >= 1; m >>= 1){ s += __shfl_xor(s, m, 64); q += __shfl_xor(q, m, 64); }
    __shared__ float ls[4], lq[4];
    int w = threadIdx.x >> 6;
    if ((threadIdx.x & 63) == 0){ ls[w] = s; lq[w] = q; }
    __syncthreads();
    if (threadIdx.x == 0){
      float S = ls[0]+ls[1]+ls[2]+ls[3], Q = lq[0]+lq[1]+lq[2]+lq[3];
      float mean = S * (1.f/1024.f);
      float var  = Q * (1.f/1024.f) - mean*mean;
      cnm[bd] = mean; cnis[bd] = rsqrtf(var + 1e-5f);
    }
    return;
  }
  if (blk < 2304){
    int rel = blk - 2048;                       // pixel-norm partials
    int x = rel & 15, y = (rel >> 4) & 7, src = rel >> 7;
    const float* in = src ? sf : cf;
    int p = x*256 + threadIdx.x;
    int b = p >> 10, pp = p & 1023;
    const float* base = in + ((size_t)(b*512 + y*64))*1024 + pp;
    float s = 0.f;
    #pragma unroll 8
    for (int d = 0; d < 64; ++d){ float xx = base[(size_t)d*1024]; s += xx*xx; }
    part[((size_t)(src*8 + y))*4096 + p] = s;
    return;
  }
  if (blk < 2336){                              // zero U+V (8192 floats)
    zUV[(blk - 2304)*256 + threadIdx.x] = 0.f;
    return;
  }
  if (blk < 2340){                              // zero BN sums (1024 floats)
    zBNS[(blk - 2336)*256 + threadIdx.x] = 0.f;
    return;
  }
  if (blk < 2356){                              // zero barrier flags (4096 u32)
    zbar[(blk - 2340)*256 + threadIdx.x] = 0u;
    return;
  }
  if (blk < 2357){                              // zero bn counters (256 u32)
    zctr[threadIdx.x] = 0u;
    return;
  }
  // ---- weight pack branch (former pack_all_k), pblk in [0,1184)
  int pblk = blk - 2357;
  const float* w; u16* wp; int CI, NCK, rel;
  if (pblk < 512){ w = w1; wp = w1p; CI = 1024; NCK = 32; rel = pblk; }
  else if (pblk < 640){ w = w2; wp = w2p; CI = 256; NCK = 8; rel = pblk - 512; }
  else if (pblk < 896){ w = w3; wp = w3p; CI = 256; NCK = 8; rel = pblk - 640; }
  else {                                        // decoder: small scatter path
    int o = (pblk - 896)*256 + threadIdx.x;     // 288 blocks x 256 = 73728
    int ci = o & 511; int r = o >> 9; int co = r & 15; int tap = r >> 4;
    wdp[o] = f2bf((co < 3) ? wd[(size_t)(co*512 + ci)*9 + tap] : 0.f);
    return;
  }
  int g = rel / NCK, ck = rel % NCK;
  __shared__ float L[16*288];                   // [co][ci_local*9+tap], 18.4 KB
  const float* base = w + ((size_t)(g*16)*CI + ck*32)*9;
  #pragma unroll
  for (int i = 0; i < 18; ++i){
    int idx = i*256 + threadIdx.x;              // 0..4607
    int row = idx / 288, col = idx - row*288;
    L[row*288 + col] = base[(size_t)row*CI*9 + col];
  }
  __syncthreads();
  u16* dst = wp + ((size_t)(g*NCK + ck)*9)*512;
  #pragma unroll
  for (int i = 0; i < 18; ++i){
    int j = i*256 + threadIdx.x;                // contiguous dest
    int tap = j >> 9, r = j & 511, lane = r >> 3, e = r & 7;
    int co = lane & 15, cil = ((lane >> 4) & 3)*8 + e;
    dst[j] = f2bf(L[co*288 + cil*9 + tap]);     // stride-9 LDS read: conflict-free
  }
}

// NCHW fp32 -> points [p][d] bf16 hi/lo split (+aux); content & style in one launch
__global__ void tsplit_k(const float* __restrict__ cf, const float* __restrict__ sf,
                         const float* __restrict__ pnp,
                         u16* __restrict__ cfh, u16* __restrict__ cfl,
                         u16* __restrict__ sfh, u16* __restrict__ sfl,
                         u16* __restrict__ tcp, u16* __restrict__ snb){
  __shared__ float tile[64][65];
  int z = blockIdx.z, is_style = z >> 2, b = z & 3;
  const float* src = is_style ? sf : cf;
  u16* hi = is_style ? sfh : cfh;
  u16* lo = is_style ? sfl : cfl;
  int p0 = blockIdx.x*64, d0 = blockIdx.y*64;
  int r = threadIdx.x >> 2, c0 = (threadIdx.x & 3) * 16;
  const float* sp = src + ((size_t)(b*512 + d0 + r))*1024 + p0 + c0;
  float v[16];
  #pragma unroll
  for (int e = 0; e < 4; ++e){
    float4 t4 = ((const float4*)sp)[e];
    v[e*4+0]=t4.x; v[e*4+1]=t4.y; v[e*4+2]=t4.z; v[e*4+3]=t4.w;
  }
  #pragma unroll
  for (int j = 0; j < 16; ++j) tile[r][c0+j] = v[j];
  if (is_style){
    u16 t16[16];
    #pragma unroll
    for (int j = 0; j < 16; ++j) t16[j] = f2bf(v[j]);
    uint4* ap = (uint4*)(snb + ((size_t)(b*512 + d0 + r))*1024 + p0 + c0);
    ap[0] = pack8(t16); ap[1] = pack8(t16+8);
  }
  __syncthreads();
  int pr = r, dc0 = c0;
  float inv;
  {
    const float* pp = pnp + (size_t)(is_style ? 8*4096 : 0) + ((b<<10) + p0 + pr);
    float s = 0.f;
    #pragma unroll
    for (int j = 0; j < 8; ++j) s += pp[j*4096];
    inv = rsqrtf(s);
  }
  u16 h16[16], l16[16], t16[16];
  #pragma unroll
  for (int j = 0; j < 16; ++j){
    float x = tile[dc0+j][pr];
    t16[j] = f2bf(x);
    float xn = x * inv;
    u16 h = f2bf(xn);
    h16[j] = h;
    l16[j] = f2bf(xn - bf2f(h));
  }
  size_t orow = (size_t)((b<<10) + p0 + pr);
  uint4* hp = (uint4*)(hi + orow*512 + d0 + dc0);
  uint4* lp = (uint4*)(lo + orow*512 + d0 + dc0);
  hp[0] = pack8(h16); hp[1] = pack8(h16+8);
  lp[0] = pack8(l16); lp[1] = pack8(l16+8);
  if (!is_style){                              // content -> packed tc chunks 16..31
    int D = d0 + dc0;
    size_t off = ((size_t)(16 + (D>>5))*4096 + orow)*32 + (D&31);
    *(uint4*)(tcp + off)     = pack8(t16);
    *(uint4*)(tcp + off + 8) = pack8(t16+8);
  }
}

// ---------------- C-GEMM: G = (cfn.sfn - 1)*SCL, split bf16, reg prefetch
__global__ __launch_bounds__(256) void cgemm_k(const u16* __restrict__ cfh, const u16* __restrict__ cfl,
        const u16* __restrict__ sfh, const u16* __restrict__ sfl,
        u16* __restrict__ G, u16* __restrict__ Gt){
  __shared__ __align__(16) u16 SH[4*128*40];   // 40 KB staging; epilogue reuses (needs 34 KB)
  u16* Ah = SH;          u16* Al = SH + 5120;
  u16* Bh = SH + 10240;  u16* Bl = SH + 15360;
  int b = blockIdx.z;
  size_t abase = ((size_t)((b<<10) + blockIdx.x*128))*512;
  size_t bbase = ((size_t)((b<<10) + blockIdx.y*128))*512;
  int lane = threadIdx.x & 63, wid = threadIdx.x >> 6;
  int wm = (wid >> 1)*64, wn = (wid & 1)*64;
  int fr = lane & 15, qd = lane >> 4;
  int sr = threadIdx.x >> 1, sc = (threadIdx.x & 1)*16;
  const u16 *pA = cfh + abase, *pB = cfl + abase, *pC = sfh + bbase, *pD = sfl + bbase;
  uint4 rA0, rA1, rB0, rB1, rC0, rC1, rD0, rD1;
  auto issue = [&](int kk){
    size_t g0 = (size_t)sr*512 + kk + sc;
    rA0 = *(const uint4*)(pA + g0); rA1 = *(const uint4*)(pA + g0 + 8);
    rB0 = *(const uint4*)(pB + g0); rB1 = *(const uint4*)(pB + g0 + 8);
    rC0 = *(const uint4*)(pC + g0); rC1 = *(const uint4*)(pC + g0 + 8);
    rD0 = *(const uint4*)(pD + g0); rD1 = *(const uint4*)(pD + g0 + 8);
  };
  f32x4 acc[4][4] = {};
  issue(0);
  for (int kk = 0; kk < 512; kk += 32){
    *(uint4*)&Ah[sr*40+sc]   = rA0; *(uint4*)&Ah[sr*40+sc+8] = rA1;
    *(uint4*)&Al[sr*40+sc]   = rB0; *(uint4*)&Al[sr*40+sc+8] = rB1;
    *(uint4*)&Bh[sr*40+sc]   = rC0; *(uint4*)&Bh[sr*40+sc+8] = rC1;
    *(uint4*)&Bl[sr*40+sc]   = rD0; *(uint4*)&Bl[sr*40+sc+8] = rD1;
    __syncthreads();
    if (kk + 32 < 512) issue(kk + 32);
    bf16x8 bhf[4], blf[4];
    #pragma unroll
    for (int ni = 0; ni < 4; ++ni){
      bhf[ni] = ldfrag(&Bh[(wn + ni*16 + fr)*40 + qd*8]);
      blf[ni] = ldfrag(&Bl[(wn + ni*16 + fr)*40 + qd*8]);
    }
    #pragma unroll
    for (int mi = 0; mi < 4; ++mi){
      bf16x8 ah = ldfrag(&Ah[(wm + mi*16 + fr)*40 + qd*8]);
      bf16x8 al = ldfrag(&Al[(wm + mi*16 + fr)*40 + qd*8]);
      #pragma unroll
      for (int ni = 0; ni < 4; ++ni){
        acc[mi][ni] = mfma16(ah, bhf[ni], acc[mi][ni]);
        acc[mi][ni] = mfma16(ah, blf[ni], acc[mi][ni]);
        acc[mi][ni] = mfma16(al, bhf[ni], acc[mi][ni]);
      }
    }
    __syncthreads();
  }
  // epilogue pass 1: C tile row-major in LDS -> coalesced G stores
  #pragma unroll
  for (int mi = 0; mi < 4; ++mi)
    #pragma unroll
    for (int ni = 0; ni < 4; ++ni)
      #pragma unroll
      for (int rg = 0; rg < 4; ++rg){
        int r = wm + mi*16 + qd*4 + rg;
        int c = wn + ni*16 + fr;
        SH[r*136 + c] = f2h((acc[mi][ni][rg] - 1.f) * SCL);
      }
  __syncthreads();
  size_t gb = (((size_t)b) << 20) + (size_t)(blockIdx.x*128)*1024 + blockIdx.y*128;
  #pragma unroll
  for (int i = 0; i < 8; ++i){
    int idx = i*256 + threadIdx.x;
    int r = idx >> 4, c4 = idx & 15;
    *(uint4*)(G + gb + (size_t)r*1024 + c4*8) = *(const uint4*)&SH[r*136 + c4*8];
  }
  // epilogue pass 2: transposed tile -> coalesced Gt stores
  __syncthreads();
  #pragma unroll
  for (int mi = 0; mi < 4; ++mi)
    #pragma unroll
    for (int ni = 0; ni < 4; ++ni)
      #pragma unroll
      for (int rg = 0; rg < 4; ++rg){
        int r = wm + mi*16 + qd*4 + rg;
        int c = wn + ni*16 + fr;
        SH[c*136 + r] = f2h((acc[mi][ni][rg] - 1.f) * SCL);
      }
  __syncthreads();
  size_t gtb = (((size_t)b) << 20) + (size_t)(blockIdx.y*128)*1024 + blockIdx.x*128;
  #pragma unroll
  for (int i = 0; i < 8; ++i){
    int idx = i*256 + threadIdx.x;
    int r = idx >> 4, c4 = idx & 15;
    *(uint4*)(Gt + gtb + (size_t)r*1024 + c4*8) = *(const uint4*)&SH[r*136 + c4*8];
  }
}

// ---------------- persistent Sinkhorn (R2 flag design) + conv1-ks1 overlay
// R9: tgemm fused as in-sink tail. After the final barrier each block holds its
// 16 full pi rows; pi -> LL[1] bf16 with XOR swizzle (idx = col ^ ((row&7)<<3),
// 2-way-conflict-free both sides, NO extra LDS so occupancy stays 2/CU and the
// flag barrier stays deadlock-free), then each wave MFMAs t[16p][64d] with
// register-prefetched B frags from snb (L2-hot). Kills tgemm launch + 16MB of
// pip traffic; t math is bit-identical to the old tgemm.
__global__ __launch_bounds__(512) void sink_k(const u16* __restrict__ G, const u16* __restrict__ Gt,
        float* __restrict__ U, float* __restrict__ V,
        u32* __restrict__ flags,
        const u16* __restrict__ cin, const u16* __restrict__ wpk,
        float* __restrict__ z1out,
        const u16* __restrict__ snb, float* __restrict__ tn, u16* __restrict__ tcp){
  __shared__ __align__(16) u16 LL[2][16*1024];  // sink: G/Gt stripes; overlay: As
  int blk = blockIdx.x;
  int tid = threadIdx.x;
  if (blk >= 256){
    // ======== overlay: conv1 ks=1 (512-thread variant of conv_k) ========
    u16* As = LL[0];                   // 128 rows x stride 40 = 10 KB
    int cbid = blk - 256;
    int cx = cbid & 15, cy = (cbid >> 4) & 3, b = cbid >> 6;
    const int NCK_TOT = 32, NCK = 16, ck0 = 16;   // ks=1: chunks 16..31
    int c0 = cy*64, r0 = cx*2;
    int lane = tid & 63, wid = tid >> 6;
    int wm = (wid >> 2)*32, wn = (wid & 3)*16;    // 8 waves: 2 px-groups x 4 co-groups
    int fr = lane & 15, qd = lane >> 4;
    int hrow = tid >> 2, ah = (tid & 3)*8;        // 512 thr x 8 bf16 = 128x32 tile
    int gy = r0 - 1 + (hrow >> 5);
    bool a_ok = ((unsigned)gy < 32u);
    size_t arow = (size_t)(b<<10) + (r0-1)*32 + hrow;
    uint4 pa = {0,0,0,0};
    auto issueA = [&](int ck){
      if (a_ok) pa = *(const uint4*)(cin + ((size_t)(ck0+ck)*4096 + arow)*32 + ah);
    };
    int g0 = (c0 + wn) >> 4;
    const u16* wb = wpk + ((size_t)g0*NCK_TOT + ck0)*9*512 + lane*8;
    f32x4 acc[2] = {};
    issueA(0);
    for (int ck = 0; ck < NCK; ++ck){
      *(uint4*)&As[hrow*40 + ah] = pa;
      __syncthreads();
      if (ck + 1 < NCK) issueA(ck + 1);
      #pragma unroll
      for (int tap = 0; tap < 9; ++tap){
        const int dy = tap/3 - 1, dx = tap%3 - 1;
        bf16x8 bf = ldfrag(wb + (size_t)(ck*9 + tap)*512);
        #pragma unroll
        for (int mi = 0; mi < 2; ++mi){
          int p0w = wm + mi*16;
          int pcol = (p0w & 31) + fr + dx;
          int lr = (p0w >> 5) + dy + 1;
          bool okc = (unsigned)pcol < 32u;
          bf16x8 af = ldfrag(&As[(lr*32 + (okc ? pcol : 0))*40 + qd*8]);
          if (!okc) af = bf16x8(0);
          acc[mi] = mfma16(af, bf, acc[mi]);
        }
      }
      __syncthreads();
    }
    #pragma unroll
    for (int mi = 0; mi < 2; ++mi)
      #pragma unroll
      for (int rg = 0; rg < 4; ++rg){
        int pp = cx*64 + wm + mi*16 + qd*4 + rg;
        int cc = c0 + wn + fr;
        size_t ro = (size_t)((b<<10) + pp);
        z1out[(size_t)4096*256 + ro*256 + cc] = acc[mi][rg];   // ks=1 half
      }
    return;
  }
  // ======== sink path (blocks 0..255) ========
  int b = blk >> 6;                    // batch group
  int sub = blk & 63;                  // block index within group
  int rb = sub << 4;                   // first row (within batch) of this block
  size_t gbase = ((size_t)((b << 10) + rb)) << 10;
  {
    const uint4* g0 = (const uint4*)(G + gbase);
    const uint4* g1 = (const uint4*)(Gt + gbase);
    uint4* d0 = (uint4*)LL[0];
    uint4* d1 = (uint4*)LL[1];
    #pragma unroll
    for (int i = 0; i < 4; ++i){
      d0[i*512 + tid] = g0[i*512 + tid];
      d1[i*512 + tid] = g1[i*512 + tid];
    }
  }
  __syncthreads();
  int wid = tid >> 6, lane = tid & 63;
  int fr = lane & 15, qd = lane >> 4;
  float* Ub = U + (b << 10);
  float* Vb = V + (b << 10);
  u32* fgrp = flags + (b << 6)*16;     // 64 flags, stride 16 u32 (one cacheline each)
  u32* fmine = fgrp + sub*16;
  int r0 = wid << 1;                   // 2 rows per wave (8 waves x 2 = 16)
  int cbase = lane << 2;               // cols cbase + k*256 + 0..3
  int budget = 1 << 21;                // failed poll rounds allowed (termination guard)

  float o0 = 0.f, o1 = 0.f;
  auto dopass = [&](int which, const float* __restrict__ inv, float* __restrict__ outv, int tgt){
    float va[16];
    #pragma unroll
    for (int k = 0; k < 4; ++k){
      #pragma unroll
      for (int j = 0; j < 2; ++j){
        float2 t = ld_agent2(inv + k*256 + cbase + j*2);
        va[k*4 + j*2]     = t.x;
        va[k*4 + j*2 + 1] = t.y;
      }
    }
    #pragma unroll
    for (int rr = 0; rr < 2; ++rr){
      int row = r0 + rr;
      float x[16]; float mx = -3.0e38f;
      #pragma unroll
      for (int k = 0; k < 4; ++k){
        uint2 g2 = *(const uint2*)(&LL[which][row*1024 + k*256 + cbase]);
        float t0 = h2f((u16)(g2.x & 0xffffu)) + va[k*4+0];
        float t1 = h2f((u16)(g2.x >> 16))     + va[k*4+1];
        float t2 = h2f((u16)(g2.y & 0xffffu)) + va[k*4+2];
        float t3 = h2f((u16)(g2.y >> 16))     + va[k*4+3];
        x[k*4+0]=t0; x[k*4+1]=t1; x[k*4+2]=t2; x[k*4+3]=t3;
        mx = fmaxf(mx, fmaxf(fmaxf(t0,t1), fmaxf(t2,t3)));
      }
      #pragma unroll
      for (int m = 32; m >= 1; m >>= 1) mx = fmaxf(mx, __shfl_xor(mx, m, 64));
      float s = 0.f;
      #pragma unroll
      for (int i = 0; i < 16; ++i) s += exp2f(x[i] - mx);
      #pragma unroll
      for (int m = 32; m >= 1; m >>= 1) s += __shfl_xor(s, m, 64);
      float o = LOG2MU - (mx + log2f(s));
      if (rr == 0) o0 = o; else o1 = o;
      if (lane == 0) st_agent(outv + rb + row, o);
    }
    // arrive: syncthreads drains all waves' output stores before the flag
    __syncthreads();
    if (tid == 0) st_agent_u32(fmine, (u32)tgt);
    if (tid < 64){                     // wave 0: poll all 64 flags, 1 load/round
      u32* fl = fgrp + tid*16;
      for (;;){
        u32 v = ld_agent_u32(fl);
        if (__all((int)(v >= (u32)tgt))) break;
        if (--budget < 0) break;       // termination guard (never hit on success)
        __builtin_amdgcn_s_sleep(1);
      }
    }
    __syncthreads();
  };

  float ku0 = 0.f, ku1 = 0.f;          // final u for this wave's rows (for pi)
  for (int it = 0; it < 20; ++it){
    dopass(0, Vb, Ub, 2*it + 1);       // u-pass: rows of G + V
    ku0 = o0; ku1 = o1;
    dopass(1, Ub, Vb, 2*it + 2);       // v-pass: rows of Gt + U
  }

  // ---- pi -> LL[1] bf16, XOR-swizzled (Gt stripe dead after final v-pass;
  // all waves passed that pass's block barrier, so overwrite is race-free)
  {
    float va[16];
    #pragma unroll
    for (int k = 0; k < 4; ++k){
      #pragma unroll
      for (int j = 0; j < 2; ++j){
        float2 t = ld_agent2(Vb + k*256 + cbase + j*2);
        va[k*4 + j*2]     = t.x;
        va[k*4 + j*2 + 1] = t.y;
      }
    }
    #pragma unroll
    for (int rr = 0; rr < 2; ++rr){
      int row = r0 + rr;
      float ur = (rr == 0 ? ku0 : ku1) + 10.f;     // +10: fold pi * 1024
      int sw = (row & 7) << 3;
      #pragma unroll
      for (int k = 0; k < 4; ++k){
        uint2 g2 = *(const uint2*)(&LL[0][row*1024 + k*256 + cbase]);
        u16 o[4];
        o[0] = f2bf(exp2f(h2f((u16)(g2.x & 0xffffu)) + va[k*4+0] + ur));
        o[1] = f2bf(exp2f(h2f((u16)(g2.x >> 16))     + va[k*4+1] + ur));
        o[2] = f2bf(exp2f(h2f((u16)(g2.y & 0xffffu)) + va[k*4+2] + ur));
        o[3] = f2bf(exp2f(h2f((u16)(g2.y >> 16))     + va[k*4+3] + ur));
        uint2 pk; pk.x = (u32)o[0] | ((u32)o[1]<<16); pk.y = (u32)o[2] | ((u32)o[3]<<16);
        *(uint2*)(&LL[1][row*1024 + ((k*256 + cbase) ^ sw)]) = pk;
      }
    }
  }
  __syncthreads();
  // ---- fused tgemm: t[16p][512d] = pi(LL[1]) @ snb^T; wave wid owns 64 d
  {
    int d0w = wid << 6;
    const u16* Bb = snb + (((size_t)(b*512 + d0w)) << 10);
    f32x4 tac[4] = {};
    uint4 pb0, pb1, pb2, pb3;
    auto issueB = [&](int ks){
      int off = ks*32 + qd*8;
      pb0 = *(const uint4*)(Bb + (((size_t)(     fr)) << 10) + off);
      pb1 = *(const uint4*)(Bb + (((size_t)(16 + fr)) << 10) + off);
      pb2 = *(const uint4*)(Bb + (((size_t)(32 + fr)) << 10) + off);
      pb3 = *(const uint4*)(Bb + (((size_t)(48 + fr)) << 10) + off);
    };
    issueB(0);
    int asw = (fr & 7) << 3;
    for (int ks = 0; ks < 32; ++ks){
      union{uint4 u; bf16x8 v;} c0_, c1_, c2_, c3_;
      c0_.u = pb0; c1_.u = pb1; c2_.u = pb2; c3_.u = pb3;
      if (ks + 1 < 32) issueB(ks + 1);
      bf16x8 af = ldfrag(&LL[1][fr*1024 + ((ks*32 + qd*8) ^ asw)]);
      tac[0] = mfma16(af, c0_.v, tac[0]);
      tac[1] = mfma16(af, c1_.v, tac[1]);
      tac[2] = mfma16(af, c2_.v, tac[2]);
      tac[3] = mfma16(af, c3_.v, tac[3]);
    }
    #pragma unroll
    for (int t = 0; t < 4; ++t)
      #pragma unroll
      for (int rg = 0; rg < 4; ++rg){
        int p = qd*4 + rg;
        int d = d0w + t*16 + fr;
        size_t ro = (size_t)((b<<10) + rb + p);
        float v = tac[t][rg];
        tn[ro*512 + d] = v;
        tcp[((size_t)(d>>5)*4096 + ro)*32 + (d&31)] = f2bf(v);
      }
  }
}

// ---------------- implicit-GEMM 3x3 conv: packed activations, frag-order weights
template<int CI, int CO, int KSPLIT, int MODE>
__global__ __launch_bounds__(256) void conv_k(const u16* __restrict__ inp, const u16* __restrict__ wpk,
        const float* __restrict__ bias, float* __restrict__ fout, u16* __restrict__ bout,
        const u16* __restrict__ tcp, const float* __restrict__ cnm, const float* __restrict__ cnis,
        const float* __restrict__ tn){
  constexpr int NCK_TOT = CI/32, NCK = NCK_TOT/KSPLIT;
  __shared__ __align__(16) u16 As[128*40];
  int b = blockIdx.z & 3, ks = blockIdx.z >> 2;
  int c0 = blockIdx.y*64;
  int r0 = blockIdx.x*2;
  int tid = threadIdx.x, lane = tid & 63, wid = tid >> 6;
  int wm = (wid >> 1)*32, wn = (wid & 1)*32;
  int fr = lane & 15, qd = lane >> 4;
  int ck0 = ks*NCK;
  int hrow = tid >> 1;
  int ah = (tid & 1)*16;
  int gy = r0 - 1 + (hrow >> 5);
  bool a_ok = ((unsigned)gy < 32u);
  size_t arow = (size_t)(b<<10) + (r0-1)*32 + hrow;
  uint4 pa0 = {0,0,0,0}, pa1 = {0,0,0,0};
  auto issueA = [&](int ck){
    if (a_ok){
      const uint4* s = (const uint4*)(inp + ((size_t)(ck0+ck)*4096 + arow)*32 + ah);
      pa0 = s[0]; pa1 = s[1];
    }
  };
  int g0 = (c0 + wn) >> 4;
  const u16* wb0 = wpk + ((size_t)(g0    )*NCK_TOT + ck0)*9*512 + lane*8;
  const u16* wb1 = wpk + ((size_t)(g0 + 1)*NCK_TOT + ck0)*9*512 + lane*8;

  f32x4 acc[2][2] = {};
  issueA(0);
  for (int ck = 0; ck < NCK; ++ck){
    *(uint4*)&As[hrow*40 + ah]     = pa0;
    *(uint4*)&As[hrow*40 + ah + 8] = pa1;
    __syncthreads();
    if (ck + 1 < NCK) issueA(ck + 1);
    #pragma unroll
    for (int tap = 0; tap < 9; ++tap){
      const int dy = tap/3 - 1, dx = tap%3 - 1;
      bf16x8 bf0 = ldfrag(wb0 + (size_t)(ck*9 + tap)*512);
      bf16x8 bf1 = ldfrag(wb1 + (size_t)(ck*9 + tap)*512);
      #pragma unroll
      for (int mi = 0; mi < 2; ++mi){
        int p0w = wm + mi*16;
        int pcol = (p0w & 31) + fr + dx;
        int lr = (p0w >> 5) + dy + 1;
        bool okc = (unsigned)pcol < 32u;
        bf16x8 af = ldfrag(&As[(lr*32 + (okc ? pcol : 0))*40 + qd*8]);
        if (!okc) af = bf16x8(0);
        acc[mi][0] = mfma16(af, bf0, acc[mi][0]);
        acc[mi][1] = mfma16(af, bf1, acc[mi][1]);
      }
    }
    __syncthreads();
  }
  #pragma unroll
  for (int mi = 0; mi < 2; ++mi)
    #pragma unroll
    for (int ni = 0; ni < 2; ++ni)
      #pragma unroll
      for (int rg = 0; rg < 4; ++rg){
        int pp = blockIdx.x*64 + wm + mi*16 + qd*4 + rg;
        int cc = c0 + wn + ni*16 + fr;
        float v = acc[mi][ni][rg];
        size_t ro = (size_t)((b<<10) + pp);
        if (MODE == 0){
          fout[(size_t)ks*4096*CO + ro*CO + cc] = v;
        } else {
          float alpha = v + bias[cc];
          float cn = (bf2f(tcp[((size_t)(16 + (cc>>5))*4096 + ro)*32 + (cc&31)])
                      - cnm[(b<<9) + cc]) * cnis[(b<<9) + cc];
          bout[((size_t)(cc>>5)*4096 + ro)*32 + (cc&31)] = f2bf(alpha*cn + tn[ro*512 + cc]);
        }
      }
}

// ---------------- decoder conv (512 -> 3): VALU reduction over packed t2
__global__ __launch_bounds__(512) void dec_k(const u16* __restrict__ t2p, const u16* __restrict__ wdp,
                                             const float* __restrict__ db, float* __restrict__ out){
  __shared__ float wlds[3*4608];
  int tid = threadIdx.x;
  for (int k = tid; k < 3*4608; k += 512){
    int c = k / 4608, rem = k - c*4608;
    int tap = rem >> 9, ci = rem & 511;
    wlds[k] = bf2f(wdp[(size_t)(tap*16 + c)*512 + ci]);
  }
  __syncthreads();
  int b = blockIdx.x >> 5;
  int p = ((blockIdx.x & 31) << 5) + (tid >> 4);
  int sub = tid & 15;
  int py = p >> 5, px = p & 31;
  float a0 = 0.f, a1 = 0.f, a2 = 0.f;
  for (int tap = 0; tap < 9; ++tap){
    int sy = py + tap/3 - 1, sx = px + tap%3 - 1;
    if (((unsigned)sy < 32u) && ((unsigned)sx < 32u)){
      size_t row = (size_t)((b<<10) + (sy<<5) + sx);
      const float* w0 = wlds + tap*512;
      #pragma unroll
      for (int j = 0; j < 4; ++j){
        int ci0 = j*128 + sub*8;
        uint4 v = *(const uint4*)(t2p + ((size_t)(ci0>>5)*4096 + row)*32 + (ci0&31));
        u32 ww[4] = {v.x, v.y, v.z, v.w};
        #pragma unroll
        for (int e = 0; e < 8; ++e){
          float x = bf2f((u16)((e & 1) ? (ww[e>>1] >> 16) : (ww[e>>1] & 0xffffu)));
          a0 += x * w0[ci0 + e];
          a1 += x * w0[4608 + ci0 + e];
          a2 += x * w0[9216 + ci0 + e];
        }
      }
    }
  }
  #pragma unroll
  for (int m = 8; m >= 1; m >>= 1){
    a0 += __shfl_xor(a0, m, 64);
    a1 += __shfl_xor(a1, m, 64);
    a2 += __shfl_xor(a2, m, 64);
  }
  if (sub == 0){
    out[((size_t)(b*3 + 0) << 10) + p] = a0 + db[0];
    out[((size_t)(b*3 + 1) << 10) + p] = a1 + db[1];
    out[((size_t)(b*3 + 2) << 10) + p] = a2 + db[2];
  }
}

// ---------------- fused BN: stats + apply in ONE kernel (internal grid sync)
// 128 blocks x 256 thr, all co-resident (<= 256 CUs) -> counter sync safe;
// budget guarantees termination. Activations stay in registers (xv fully
// unrolled -> no scratch), eliminating the 8MB z re-read of the old 2-kernel
// scheme. x = relu(za+zb+bias); ap = bf16(x*sc + sh) in packed layout.
__global__ __launch_bounds__(256) void bn_k(const float* __restrict__ z, const float* __restrict__ bias,
                    float* __restrict__ sums, const float* __restrict__ gamma,
                    const float* __restrict__ beta, u16* __restrict__ ap,
                    u32* __restrict__ ctr){
  int c = threadIdx.x;
  int r0 = blockIdx.x*32;
  float bi = bias[c];
  float xv[32];
  float s = 0.f, q = 0.f;
  #pragma unroll
  for (int i = 0; i < 32; ++i){
    size_t ro = (size_t)(r0 + i)*256 + c;
    float x = fmaxf(z[ro] + z[(size_t)4096*256 + ro] + bi, 0.f);
    xv[i] = x; s += x; q += x*x;
  }
  atomicAdd(&sums[c], s);
  atomicAdd(&sums[256 + c], q);
  __syncthreads();                     // drains atomics (vmcnt 0 before barrier)
  if (c == 0){
    __hip_atomic_fetch_add(ctr, 1u, __ATOMIC_RELAXED, __HIP_MEMORY_SCOPE_AGENT);
    int budget = 1 << 21;
    while (ld_agent_u32(ctr) < 128u && --budget > 0) __builtin_amdgcn_s_sleep(1);
  }
  __syncthreads();
  float S = ld_agentf(&sums[c]), Q = ld_agentf(&sums[256 + c]);
  float mean = S * (1.f/4096.f);
  float var  = Q * (1.f/4096.f) - mean*mean;
  float sc = gamma[c] * rsqrtf(var + 1e-5f);
  float sh = beta[c] - mean*sc;
  u16* apc = ap + ((size_t)(c>>5)*4096)*32 + (c&31);
  #pragma unroll
  for (int i = 0; i < 32; ++i)
    apc[(size_t)(r0 + i)*32] = f2bf(xv[i]*sc + sh);
}

// ---------------- launch ----------------
extern "C" void kernel_launch(void* const* d_in, const int* in_sizes, int n_in,
                              void* d_out, int out_size, void* d_ws, size_t ws_size,
                              hipStream_t stream){
  const float* cf  = (const float*)d_in[0];
  const float* sf  = (const float*)d_in[1];
  const float* w1  = (const float*)d_in[2];
  const float* b1  = (const float*)d_in[3];
  const float* g1  = (const float*)d_in[4];
  const float* be1 = (const float*)d_in[5];
  const float* w2  = (const float*)d_in[6];
  const float* b2  = (const float*)d_in[7];
  const float* g2  = (const float*)d_in[8];
  const float* be2 = (const float*)d_in[9];
  const float* w3  = (const float*)d_in[10];
  const float* b3  = (const float*)d_in[11];
  const float* dw  = (const float*)d_in[12];
  const float* db  = (const float*)d_in[13];

  char* ws = (char*)d_ws;
  u16* G    = (u16*)(ws + OFF_G);
  u16* Gt   = (u16*)(ws + OFF_GT);
  float* U    = (float*)(ws + OFF_U);
  float* V    = (float*)(ws + OFF_V);
  u32* bar    = (u32*)(ws + OFF_BAR);
  u32* ctr    = (u32*)(ws + OFF_CTR);
  float* cnm  = (float*)(ws + OFF_CNM);
  float* cnis = (float*)(ws + OFF_CNIS);
  float* bns1 = (float*)(ws + OFF_BNS);
  float* bns2 = bns1 + 512;
  float* pnp  = (float*)(ws + OFF_PNP);
  u16* cfh = (u16*)(ws + OFF_CFH);
  u16* cfl = (u16*)(ws + OFF_CFL);
  u16* sfh = (u16*)(ws + OFF_SFH);
  u16* sfl = (u16*)(ws + OFF_SFL);
  u16* snb = (u16*)(ws + OFF_SNB);
  float* tn  = (float*)(ws + OFF_TN);
  u16* tcp = (u16*)(ws + OFF_TCP);
  u16* w1p = (u16*)(ws + OFF_W1P);
  u16* w2p = (u16*)(ws + OFF_W2P);
  u16* w3p = (u16*)(ws + OFF_W3P);
  u16* wdp = (u16*)(ws + OFF_WDP);
  float* z1  = (float*)(ws + OFF_Z1);
  u16*   a1p = (u16*)(ws + OFF_A1P);
  float* z2  = (float*)(ws + OFF_Z2);
  u16*   a2p = (u16*)(ws + OFF_A2P);
  u16*   t2p = (u16*)(ws + OFF_T2P);

  // fused: stats + zeroing + weight pack (one launch)
  stats_k<<<3541, 256, 0, stream>>>(cf, sf, cnm, cnis, pnp, U, bns1, bar, ctr,
                                    w1, w2, w3, dw, w1p, w2p, w3p, wdp);
  tsplit_k<<<dim3(16, 8, 8), 256, 0, stream>>>(cf, sf, pnp, cfh, cfl, sfh, sfl, tcp, snb);

  cgemm_k<<<dim3(8, 8, 4), 256, 0, stream>>>(cfh, cfl, sfh, sfl, G, Gt);

  // Sinkhorn + pi + fused tgemm (blocks 0-255) + conv1 ks=1 overlay (256-511)
  sink_k<<<512, 512, 0, stream>>>(G, Gt, U, V, bar, tcp, w1p, z1, snb, tn, tcp);

  // conv1 ks=0 half (t channels) -- ks=1 done in sink overlay
  conv_k<1024, 256, 2, 0><<<dim3(16, 4, 4), 256, 0, stream>>>(
      tcp, w1p, nullptr, z1, nullptr, nullptr, nullptr, nullptr, nullptr);
  bn_k<<<128, 256, 0, stream>>>(z1, b1, bns1, g1, be1, a1p, ctr);

  conv_k<256, 256, 2, 0><<<dim3(16, 4, 8), 256, 0, stream>>>(
      a1p, w2p, nullptr, z2, nullptr, nullptr, nullptr, nullptr, nullptr);
  bn_k<<<128, 256, 0, stream>>>(z2, b2, bns2, g2, be2, a2p, ctr + 16);

  conv_k<256, 512, 1, 1><<<dim3(16, 8, 4), 256, 0, stream>>>(
      a2p, w3p, b3, nullptr, t2p, tcp, cnm, cnis, tn);

  dec_k<<<128, 512, 0, stream>>>(t2p, wdp, db, (float*)d_out);

  (void)in_sizes; (void)n_in; (void)out_size; (void)ws_size;
}

// Round 10
// 389.460 us; speedup vs baseline: 1.0280x; 1.0280x over previous
//
#include <hip/hip_runtime.h>

typedef unsigned short u16;
typedef unsigned int u32;
typedef unsigned long long u64;
typedef float f32x4 __attribute__((ext_vector_type(4)));
typedef short bf16x8 __attribute__((ext_vector_type(8)));   // 8 bf16 bit-patterns (4 VGPRs)

#define DEV static __device__ __forceinline__

DEV float bf2f(u16 u){ union{float f; u32 i;} x; x.i = ((u32)u) << 16; return x.f; }
DEV u16 f2bf(float f){ union{float f; u32 i;} x; x.f = f; u32 u = x.i;
  return (u16)((u + 0x7fffu + ((u >> 16) & 1u)) >> 16); }           // RNE
DEV u16 f2h(float f){ _Float16 h = (_Float16)f; u16 u; __builtin_memcpy(&u, &h, 2); return u; }
DEV float h2f(u16 u){ _Float16 h; __builtin_memcpy(&h, &u, 2); return (float)h; }
DEV uint4 pack8(const u16* s){ uint4 v;
  v.x = (u32)s[0] | ((u32)s[1]<<16); v.y = (u32)s[2] | ((u32)s[3]<<16);
  v.z = (u32)s[4] | ((u32)s[5]<<16); v.w = (u32)s[6] | ((u32)s[7]<<16); return v; }
DEV f32x4 mfma16(bf16x8 a, bf16x8 b, f32x4 c){
  return __builtin_amdgcn_mfma_f32_16x16x32_bf16(a, b, c, 0, 0, 0);
}
DEV bf16x8 ldfrag(const u16* p){ return *(const bf16x8*)p; }

// agent-scope relaxed atomics (sc0/sc1: MALL-coherent, nothing dirty in XCD L2)
DEV void st_agent(float* p, float v){
  __hip_atomic_store(p, v, __ATOMIC_RELAXED, __HIP_MEMORY_SCOPE_AGENT); }
DEV float ld_agentf(const float* p){
  return __hip_atomic_load(p, __ATOMIC_RELAXED, __HIP_MEMORY_SCOPE_AGENT); }
DEV float2 ld_agent2(const float* p){
  u64 u = __hip_atomic_load((const u64*)p, __ATOMIC_RELAXED, __HIP_MEMORY_SCOPE_AGENT);
  union{u64 u; float2 f;} c; c.u = u; return c.f; }
DEV void st_agent_u32(u32* p, u32 v){
  __hip_atomic_store(p, v, __ATOMIC_RELAXED, __HIP_MEMORY_SCOPE_AGENT); }
DEV u32 ld_agent_u32(const u32* p){
  return __hip_atomic_load(p, __ATOMIC_RELAXED, __HIP_MEMORY_SCOPE_AGENT); }

constexpr float SCL = 144.269504088896341f;    // 100*log2(e) = 1/(eps*ln2), eps=0.01
constexpr float LOG2MU = -9.99998522680257f;   // log2(1/1024 + 1e-8)

// ---------------- workspace layout ----------------
// Packed activation layout AP[ck][row=b*1024+px][32]: elem = (ck*4096+row)*32+c
constexpr size_t MB = 1ull << 20;
constexpr size_t OFF_G    = 0;                 // f16 [4][1024][1024]
constexpr size_t OFF_GT   = 8*MB;              // f16 transpose
constexpr size_t OFF_U    = 16*MB;             // fp32 [4][1024]
constexpr size_t OFF_V    = OFF_U   + (16<<10);
constexpr size_t OFF_BAR  = OFF_V   + (16<<10);// barrier flags u32 [4][64][16] (64B stride)
constexpr size_t OFF_CTR  = OFF_BAR + (16<<10);// bn counters u32[256] (2 used, 64B apart)
constexpr size_t OFF_CNM  = OFF_CTR + (16<<10);
constexpr size_t OFF_CNIS = OFF_CNM + (8<<10);
constexpr size_t OFF_BNS  = OFF_CNIS+ (8<<10);
constexpr size_t OFF_PNP  = OFF_BNS + (4<<10); // pixel-norm partials [2][8][4096] f32 = 256 KB
constexpr size_t OFF_CFH  = 17*MB;             // bf16 [4][1024][512]
constexpr size_t OFF_CFL  = 21*MB;
constexpr size_t OFF_SFH  = 25*MB;
constexpr size_t OFF_SFL  = 29*MB;
constexpr size_t OFF_SNB  = 33*MB;             // bf16 style NCHW [4][512][1024]
constexpr size_t OFF_TN   = 37*MB;             // fp32 t NHWC [4][1024][512]
constexpr size_t OFF_TCP  = 45*MB;             // bf16 packed concat: 32 chunks
constexpr size_t OFF_W1P  = 53*MB;             // frag-order bf16 weights
constexpr size_t OFF_W2P  = OFF_W1P + 9*256*1024*2;
constexpr size_t OFF_W3P  = OFF_W2P + 9*256*256*2;
constexpr size_t OFF_WDP  = OFF_W3P + 9*512*256*2;   // [9][16][512]
constexpr size_t OFF_PIP  = 62*MB;             // bf16 pi packed [4][1024][1024]
// reuse (dead after cgemm/tgemm):
constexpr size_t OFF_Z1  = 17*MB;              // fp32 partials 2x[4096][256]
constexpr size_t OFF_A1P = 25*MB;              // packed bf16, 8 chunks
constexpr size_t OFF_Z2  = 27*MB;              // fp32 partials 2x[4096][256]
constexpr size_t OFF_A2P = 35*MB;              // packed bf16, 8 chunks
constexpr size_t OFF_T2P = 17*MB;              // packed bf16, 16 chunks (z1 dead)

// ---------------- fused stats + weight pack:
//   chan_stats (0..2047) + pix_part (2048..2303) + zero UV (2304..2335)
//   + zero BN sums (2336..2339) + zero flags (2340..2355) + zero bn ctrs (2356)
//   + pack (2357..3540)
__global__ void stats_k(const float* __restrict__ cf, const float* __restrict__ sf,
                        float* __restrict__ cnm, float* __restrict__ cnis,
                        float* __restrict__ part, float* __restrict__ zUV,
                        float* __restrict__ zBNS, u32* __restrict__ zbar,
                        u32* __restrict__ zctr,
                        const float* __restrict__ w1, const float* __restrict__ w2,
                        const float* __restrict__ w3, const float* __restrict__ wd,
                        u16* __restrict__ w1p, u16* __restrict__ w2p,
                        u16* __restrict__ w3p, u16* __restrict__ wdp){
  int blk = blockIdx.x;
  if (blk < 2048){                              // content channel stats
    int bd = blk;
    float4 v = ((const float4*)(cf + (size_t)bd*1024))[threadIdx.x];
    float s = v.x+v.y+v.z+v.w;
    float q = v.x*v.x+v.y*v.y+v.z*v.z+v.w*v.w;
    #pragma unroll
    for (int m = 32; m >= 1; m >>= 1){ s += __shfl_xor(s, m, 64); q += __shfl_xor(q, m, 64); }
    __shared__ float ls[4], lq[4];
    int w = threadIdx.x >> 6;
    if ((threadIdx.x & 63) == 0){ ls[w] = s; lq[w] = q; }
    __syncthreads();
    if (threadIdx.x == 0){
      float S = ls[0]+ls[1]+ls[2]+ls[3], Q = lq[0]+lq[1]+lq[2]+lq[3];
      float mean = S * (1.f/1024.f);
      float var  = Q * (1.f/1024.f) - mean*mean;
      cnm[bd] = mean; cnis[bd] = rsqrtf(var + 1e-5f);
    }
    return;
  }
  if (blk < 2304){
    int rel = blk - 2048;                       // pixel-norm partials
    int x = rel & 15, y = (rel >> 4) & 7, src = rel >> 7;
    const float* in = src ? sf : cf;
    int p = x*256 + threadIdx.x;
    int b = p >> 10, pp = p & 1023;
    const float* base = in + ((size_t)(b*512 + y*64))*1024 + pp;
    float s = 0.f;
    #pragma unroll 8
    for (int d = 0; d < 64; ++d){ float xx = base[(size_t)d*1024]; s += xx*xx; }
    part[((size_t)(src*8 + y))*4096 + p] = s;
    return;
  }
  if (blk < 2336){                              // zero U+V (8192 floats)
    zUV[(blk - 2304)*256 + threadIdx.x] = 0.f;
    return;
  }
  if (blk < 2340){                              // zero BN sums (1024 floats)
    zBNS[(blk - 2336)*256 + threadIdx.x] = 0.f;
    return;
  }
  if (blk < 2356){                              // zero barrier flags (4096 u32)
    zbar[(blk - 2340)*256 + threadIdx.x] = 0u;
    return;
  }
  if (blk < 2357){                              // zero bn counters (256 u32)
    zctr[threadIdx.x] = 0u;
    return;
  }
  // ---- weight pack branch (former pack_all_k), pblk in [0,1184)
  int pblk = blk - 2357;
  const float* w; u16* wp; int CI, NCK, rel;
  if (pblk < 512){ w = w1; wp = w1p; CI = 1024; NCK = 32; rel = pblk; }
  else if (pblk < 640){ w = w2; wp = w2p; CI = 256; NCK = 8; rel = pblk - 512; }
  else if (pblk < 896){ w = w3; wp = w3p; CI = 256; NCK = 8; rel = pblk - 640; }
  else {                                        // decoder: small scatter path
    int o = (pblk - 896)*256 + threadIdx.x;     // 288 blocks x 256 = 73728
    int ci = o & 511; int r = o >> 9; int co = r & 15; int tap = r >> 4;
    wdp[o] = f2bf((co < 3) ? wd[(size_t)(co*512 + ci)*9 + tap] : 0.f);
    return;
  }
  int g = rel / NCK, ck = rel % NCK;
  __shared__ float L[16*288];                   // [co][ci_local*9+tap], 18.4 KB
  const float* base = w + ((size_t)(g*16)*CI + ck*32)*9;
  #pragma unroll
  for (int i = 0; i < 18; ++i){
    int idx = i*256 + threadIdx.x;              // 0..4607
    int row = idx / 288, col = idx - row*288;
    L[row*288 + col] = base[(size_t)row*CI*9 + col];
  }
  __syncthreads();
  u16* dst = wp + ((size_t)(g*NCK + ck)*9)*512;
  #pragma unroll
  for (int i = 0; i < 18; ++i){
    int j = i*256 + threadIdx.x;                // contiguous dest
    int tap = j >> 9, r = j & 511, lane = r >> 3, e = r & 7;
    int co = lane & 15, cil = ((lane >> 4) & 3)*8 + e;
    dst[j] = f2bf(L[co*288 + cil*9 + tap]);     // stride-9 LDS read: conflict-free
  }
}

// NCHW fp32 -> points [p][d] bf16 hi/lo split (+aux); content & style in one launch
__global__ void tsplit_k(const float* __restrict__ cf, const float* __restrict__ sf,
                         const float* __restrict__ pnp,
                         u16* __restrict__ cfh, u16* __restrict__ cfl,
                         u16* __restrict__ sfh, u16* __restrict__ sfl,
                         u16* __restrict__ tcp, u16* __restrict__ snb){
  __shared__ float tile[64][65];
  int z = blockIdx.z, is_style = z >> 2, b = z & 3;
  const float* src = is_style ? sf : cf;
  u16* hi = is_style ? sfh : cfh;
  u16* lo = is_style ? sfl : cfl;
  int p0 = blockIdx.x*64, d0 = blockIdx.y*64;
  int r = threadIdx.x >> 2, c0 = (threadIdx.x & 3) * 16;
  const float* sp = src + ((size_t)(b*512 + d0 + r))*1024 + p0 + c0;
  float v[16];
  #pragma unroll
  for (int e = 0; e < 4; ++e){
    float4 t4 = ((const float4*)sp)[e];
    v[e*4+0]=t4.x; v[e*4+1]=t4.y; v[e*4+2]=t4.z; v[e*4+3]=t4.w;
  }
  #pragma unroll
  for (int j = 0; j < 16; ++j) tile[r][c0+j] = v[j];
  if (is_style){
    u16 t16[16];
    #pragma unroll
    for (int j = 0; j < 16; ++j) t16[j] = f2bf(v[j]);
    uint4* ap = (uint4*)(snb + ((size_t)(b*512 + d0 + r))*1024 + p0 + c0);
    ap[0] = pack8(t16); ap[1] = pack8(t16+8);
  }
  __syncthreads();
  int pr = r, dc0 = c0;
  float inv;
  {
    const float* pp = pnp + (size_t)(is_style ? 8*4096 : 0) + ((b<<10) + p0 + pr);
    float s = 0.f;
    #pragma unroll
    for (int j = 0; j < 8; ++j) s += pp[j*4096];
    inv = rsqrtf(s);
  }
  u16 h16[16], l16[16], t16[16];
  #pragma unroll
  for (int j = 0; j < 16; ++j){
    float x = tile[dc0+j][pr];
    t16[j] = f2bf(x);
    float xn = x * inv;
    u16 h = f2bf(xn);
    h16[j] = h;
    l16[j] = f2bf(xn - bf2f(h));
  }
  size_t orow = (size_t)((b<<10) + p0 + pr);
  uint4* hp = (uint4*)(hi + orow*512 + d0 + dc0);
  uint4* lp = (uint4*)(lo + orow*512 + d0 + dc0);
  hp[0] = pack8(h16); hp[1] = pack8(h16+8);
  lp[0] = pack8(l16); lp[1] = pack8(l16+8);
  if (!is_style){                              // content -> packed tc chunks 16..31
    int D = d0 + dc0;
    size_t off = ((size_t)(16 + (D>>5))*4096 + orow)*32 + (D&31);
    *(uint4*)(tcp + off)     = pack8(t16);
    *(uint4*)(tcp + off + 8) = pack8(t16+8);
  }
}

// ---------------- C-GEMM: G = (cfn.sfn - 1)*SCL, split bf16, reg prefetch
__global__ __launch_bounds__(256) void cgemm_k(const u16* __restrict__ cfh, const u16* __restrict__ cfl,
        const u16* __restrict__ sfh, const u16* __restrict__ sfl,
        u16* __restrict__ G, u16* __restrict__ Gt){
  __shared__ __align__(16) u16 SH[4*128*40];   // 40 KB staging; epilogue reuses (needs 34 KB)
  u16* Ah = SH;          u16* Al = SH + 5120;
  u16* Bh = SH + 10240;  u16* Bl = SH + 15360;
  int b = blockIdx.z;
  size_t abase = ((size_t)((b<<10) + blockIdx.x*128))*512;
  size_t bbase = ((size_t)((b<<10) + blockIdx.y*128))*512;
  int lane = threadIdx.x & 63, wid = threadIdx.x >> 6;
  int wm = (wid >> 1)*64, wn = (wid & 1)*64;
  int fr = lane & 15, qd = lane >> 4;
  int sr = threadIdx.x >> 1, sc = (threadIdx.x & 1)*16;
  const u16 *pA = cfh + abase, *pB = cfl + abase, *pC = sfh + bbase, *pD = sfl + bbase;
  uint4 rA0, rA1, rB0, rB1, rC0, rC1, rD0, rD1;
  auto issue = [&](int kk){
    size_t g0 = (size_t)sr*512 + kk + sc;
    rA0 = *(const uint4*)(pA + g0); rA1 = *(const uint4*)(pA + g0 + 8);
    rB0 = *(const uint4*)(pB + g0); rB1 = *(const uint4*)(pB + g0 + 8);
    rC0 = *(const uint4*)(pC + g0); rC1 = *(const uint4*)(pC + g0 + 8);
    rD0 = *(const uint4*)(pD + g0); rD1 = *(const uint4*)(pD + g0 + 8);
  };
  f32x4 acc[4][4] = {};
  issue(0);
  for (int kk = 0; kk < 512; kk += 32){
    *(uint4*)&Ah[sr*40+sc]   = rA0; *(uint4*)&Ah[sr*40+sc+8] = rA1;
    *(uint4*)&Al[sr*40+sc]   = rB0; *(uint4*)&Al[sr*40+sc+8] = rB1;
    *(uint4*)&Bh[sr*40+sc]   = rC0; *(uint4*)&Bh[sr*40+sc+8] = rC1;
    *(uint4*)&Bl[sr*40+sc]   = rD0; *(uint4*)&Bl[sr*40+sc+8] = rD1;
    __syncthreads();
    if (kk + 32 < 512) issue(kk + 32);
    bf16x8 bhf[4], blf[4];
    #pragma unroll
    for (int ni = 0; ni < 4; ++ni){
      bhf[ni] = ldfrag(&Bh[(wn + ni*16 + fr)*40 + qd*8]);
      blf[ni] = ldfrag(&Bl[(wn + ni*16 + fr)*40 + qd*8]);
    }
    #pragma unroll
    for (int mi = 0; mi < 4; ++mi){
      bf16x8 ah = ldfrag(&Ah[(wm + mi*16 + fr)*40 + qd*8]);
      bf16x8 al = ldfrag(&Al[(wm + mi*16 + fr)*40 + qd*8]);
      #pragma unroll
      for (int ni = 0; ni < 4; ++ni){
        acc[mi][ni] = mfma16(ah, bhf[ni], acc[mi][ni]);
        acc[mi][ni] = mfma16(ah, blf[ni], acc[mi][ni]);
        acc[mi][ni] = mfma16(al, bhf[ni], acc[mi][ni]);
      }
    }
    __syncthreads();
  }
  // epilogue pass 1: C tile row-major in LDS -> coalesced G stores
  #pragma unroll
  for (int mi = 0; mi < 4; ++mi)
    #pragma unroll
    for (int ni = 0; ni < 4; ++ni)
      #pragma unroll
      for (int rg = 0; rg < 4; ++rg){
        int r = wm + mi*16 + qd*4 + rg;
        int c = wn + ni*16 + fr;
        SH[r*136 + c] = f2h((acc[mi][ni][rg] - 1.f) * SCL);
      }
  __syncthreads();
  size_t gb = (((size_t)b) << 20) + (size_t)(blockIdx.x*128)*1024 + blockIdx.y*128;
  #pragma unroll
  for (int i = 0; i < 8; ++i){
    int idx = i*256 + threadIdx.x;
    int r = idx >> 4, c4 = idx & 15;
    *(uint4*)(G + gb + (size_t)r*1024 + c4*8) = *(const uint4*)&SH[r*136 + c4*8];
  }
  // epilogue pass 2: transposed tile -> coalesced Gt stores
  __syncthreads();
  #pragma unroll
  for (int mi = 0; mi < 4; ++mi)
    #pragma unroll
    for (int ni = 0; ni < 4; ++ni)
      #pragma unroll
      for (int rg = 0; rg < 4; ++rg){
        int r = wm + mi*16 + qd*4 + rg;
        int c = wn + ni*16 + fr;
        SH[c*136 + r] = f2h((acc[mi][ni][rg] - 1.f) * SCL);
      }
  __syncthreads();
  size_t gtb = (((size_t)b) << 20) + (size_t)(blockIdx.y*128)*1024 + blockIdx.x*128;
  #pragma unroll
  for (int i = 0; i < 8; ++i){
    int idx = i*256 + threadIdx.x;
    int r = idx >> 4, c4 = idx & 15;
    *(uint4*)(Gt + gtb + (size_t)r*1024 + c4*8) = *(const uint4*)&SH[r*136 + c4*8];
  }
}

// ---------------- persistent Sinkhorn (R2 flag design) + conv1-ks1 overlay
// R10: reverted R9's in-sink tgemm (FETCH 28->44GB, sink +27us: per-block snb
// re-reads at 2 blocks/CU on half the chip lose to the standalone LDS-tiled
// tgemm). pi epilogue writes pip again; tgemm_k restored.
__global__ __launch_bounds__(512) void sink_k(const u16* __restrict__ G, const u16* __restrict__ Gt,
        float* __restrict__ U, float* __restrict__ V,
        u32* __restrict__ flags, u16* __restrict__ pip,
        const u16* __restrict__ cin, const u16* __restrict__ wpk,
        float* __restrict__ z1out){
  __shared__ __align__(16) u16 LL[2][16*1024];  // sink: G/Gt stripes; overlay: As
  int blk = blockIdx.x;
  int tid = threadIdx.x;
  if (blk >= 256){
    // ======== overlay: conv1 ks=1 (512-thread variant of conv_k) ========
    u16* As = LL[0];                   // 128 rows x stride 40 = 10 KB
    int cbid = blk - 256;
    int cx = cbid & 15, cy = (cbid >> 4) & 3, b = cbid >> 6;
    const int NCK_TOT = 32, NCK = 16, ck0 = 16;   // ks=1: chunks 16..31
    int c0 = cy*64, r0 = cx*2;
    int lane = tid & 63, wid = tid >> 6;
    int wm = (wid >> 2)*32, wn = (wid & 3)*16;    // 8 waves: 2 px-groups x 4 co-groups
    int fr = lane & 15, qd = lane >> 4;
    int hrow = tid >> 2, ah = (tid & 3)*8;        // 512 thr x 8 bf16 = 128x32 tile
    int gy = r0 - 1 + (hrow >> 5);
    bool a_ok = ((unsigned)gy < 32u);
    size_t arow = (size_t)(b<<10) + (r0-1)*32 + hrow;
    uint4 pa = {0,0,0,0};
    auto issueA = [&](int ck){
      if (a_ok) pa = *(const uint4*)(cin + ((size_t)(ck0+ck)*4096 + arow)*32 + ah);
    };
    int g0 = (c0 + wn) >> 4;
    const u16* wb = wpk + ((size_t)g0*NCK_TOT + ck0)*9*512 + lane*8;
    f32x4 acc[2] = {};
    issueA(0);
    for (int ck = 0; ck < NCK; ++ck){
      *(uint4*)&As[hrow*40 + ah] = pa;
      __syncthreads();
      if (ck + 1 < NCK) issueA(ck + 1);
      #pragma unroll
      for (int tap = 0; tap < 9; ++tap){
        const int dy = tap/3 - 1, dx = tap%3 - 1;
        bf16x8 bf = ldfrag(wb + (size_t)(ck*9 + tap)*512);
        #pragma unroll
        for (int mi = 0; mi < 2; ++mi){
          int p0w = wm + mi*16;
          int pcol = (p0w & 31) + fr + dx;
          int lr = (p0w >> 5) + dy + 1;
          bool okc = (unsigned)pcol < 32u;
          bf16x8 af = ldfrag(&As[(lr*32 + (okc ? pcol : 0))*40 + qd*8]);
          if (!okc) af = bf16x8(0);
          acc[mi] = mfma16(af, bf, acc[mi]);
        }
      }
      __syncthreads();
    }
    #pragma unroll
    for (int mi = 0; mi < 2; ++mi)
      #pragma unroll
      for (int rg = 0; rg < 4; ++rg){
        int pp = cx*64 + wm + mi*16 + qd*4 + rg;
        int cc = c0 + wn + fr;
        size_t ro = (size_t)((b<<10) + pp);
        z1out[(size_t)4096*256 + ro*256 + cc] = acc[mi][rg];   // ks=1 half
      }
    return;
  }
  // ======== sink path (blocks 0..255) ========
  int b = blk >> 6;                    // batch group
  int sub = blk & 63;                  // block index within group
  int rb = sub << 4;                   // first row (within batch) of this block
  size_t gbase = ((size_t)((b << 10) + rb)) << 10;
  {
    const uint4* g0 = (const uint4*)(G + gbase);
    const uint4* g1 = (const uint4*)(Gt + gbase);
    uint4* d0 = (uint4*)LL[0];
    uint4* d1 = (uint4*)LL[1];
    #pragma unroll
    for (int i = 0; i < 4; ++i){
      d0[i*512 + tid] = g0[i*512 + tid];
      d1[i*512 + tid] = g1[i*512 + tid];
    }
  }
  __syncthreads();
  int wid = tid >> 6, lane = tid & 63;
  float* Ub = U + (b << 10);
  float* Vb = V + (b << 10);
  u32* fgrp = flags + (b << 6)*16;     // 64 flags, stride 16 u32 (one cacheline each)
  u32* fmine = fgrp + sub*16;
  int r0 = wid << 1;                   // 2 rows per wave (8 waves x 2 = 16)
  int cbase = lane << 2;               // cols cbase + k*256 + 0..3
  int budget = 1 << 21;                // failed poll rounds allowed (termination guard)

  float o0 = 0.f, o1 = 0.f;
  auto dopass = [&](int which, const float* __restrict__ inv, float* __restrict__ outv, int tgt){
    float va[16];
    #pragma unroll
    for (int k = 0; k < 4; ++k){
      #pragma unroll
      for (int j = 0; j < 2; ++j){
        float2 t = ld_agent2(inv + k*256 + cbase + j*2);
        va[k*4 + j*2]     = t.x;
        va[k*4 + j*2 + 1] = t.y;
      }
    }
    #pragma unroll
    for (int rr = 0; rr < 2; ++rr){
      int row = r0 + rr;
      float x[16]; float mx = -3.0e38f;
      #pragma unroll
      for (int k = 0; k < 4; ++k){
        uint2 g2 = *(const uint2*)(&LL[which][row*1024 + k*256 + cbase]);
        float t0 = h2f((u16)(g2.x & 0xffffu)) + va[k*4+0];
        float t1 = h2f((u16)(g2.x >> 16))     + va[k*4+1];
        float t2 = h2f((u16)(g2.y & 0xffffu)) + va[k*4+2];
        float t3 = h2f((u16)(g2.y >> 16))     + va[k*4+3];
        x[k*4+0]=t0; x[k*4+1]=t1; x[k*4+2]=t2; x[k*4+3]=t3;
        mx = fmaxf(mx, fmaxf(fmaxf(t0,t1), fmaxf(t2,t3)));
      }
      #pragma unroll
      for (int m = 32; m >= 1; m >>= 1) mx = fmaxf(mx, __shfl_xor(mx, m, 64));
      float s = 0.f;
      #pragma unroll
      for (int i = 0; i < 16; ++i) s += exp2f(x[i] - mx);
      #pragma unroll
      for (int m = 32; m >= 1; m >>= 1) s += __shfl_xor(s, m, 64);
      float o = LOG2MU - (mx + log2f(s));
      if (rr == 0) o0 = o; else o1 = o;
      if (lane == 0) st_agent(outv + rb + row, o);
    }
    // arrive: syncthreads drains all waves' output stores before the flag
    __syncthreads();
    if (tid == 0) st_agent_u32(fmine, (u32)tgt);
    if (tid < 64){                     // wave 0: poll all 64 flags, 1 load/round
      u32* fl = fgrp + tid*16;
      for (;;){
        u32 v = ld_agent_u32(fl);
        if (__all((int)(v >= (u32)tgt))) break;
        if (--budget < 0) break;       // termination guard (never hit on success)
        __builtin_amdgcn_s_sleep(1);
      }
    }
    __syncthreads();
  };

  float ku0 = 0.f, ku1 = 0.f;          // final u for this wave's rows (for pi)
  for (int it = 0; it < 20; ++it){
    dopass(0, Vb, Ub, 2*it + 1);       // u-pass: rows of G + V
    ku0 = o0; ku1 = o1;
    dopass(1, Ub, Vb, 2*it + 2);       // v-pass: rows of Gt + U
  }

  // ---- pi epilogue: pip = bf16(2^(G + u + v + 10))
  float va[16];
  #pragma unroll
  for (int k = 0; k < 4; ++k){
    #pragma unroll
    for (int j = 0; j < 2; ++j){
      float2 t = ld_agent2(Vb + k*256 + cbase + j*2);
      va[k*4 + j*2]     = t.x;
      va[k*4 + j*2 + 1] = t.y;
    }
  }
  #pragma unroll
  for (int rr = 0; rr < 2; ++rr){
    int row = r0 + rr;
    float ur = (rr == 0 ? ku0 : ku1) + 10.f;       // +10: fold pi * 1024
    size_t orow = ((size_t)((b << 10) + rb + row)) << 10;
    #pragma unroll
    for (int k = 0; k < 4; ++k){
      uint2 g2 = *(const uint2*)(&LL[0][row*1024 + k*256 + cbase]);
      u16 o[4];
      o[0] = f2bf(exp2f(h2f((u16)(g2.x & 0xffffu)) + va[k*4+0] + ur));
      o[1] = f2bf(exp2f(h2f((u16)(g2.x >> 16))     + va[k*4+1] + ur));
      o[2] = f2bf(exp2f(h2f((u16)(g2.y & 0xffffu)) + va[k*4+2] + ur));
      o[3] = f2bf(exp2f(h2f((u16)(g2.y >> 16))     + va[k*4+3] + ur));
      uint2 pk; pk.x = (u32)o[0] | ((u32)o[1]<<16); pk.y = (u32)o[2] | ((u32)o[3]<<16);
      *(uint2*)(pip + orow + k*256 + cbase) = pk;
    }
  }
}

// ---------------- t = pi @ sf: pure bf16 GEMM, 64p x 128d tiles, reg prefetch
__global__ __launch_bounds__(256) void tgemm_k(const u16* __restrict__ pip,
        const u16* __restrict__ snb, float* __restrict__ tn, u16* __restrict__ tcp){
  __shared__ __align__(16) u16 As[64*40], Bs[128*40];
  int b = blockIdx.z, p0 = blockIdx.x*64, d0 = blockIdx.y*128;
  int tid = threadIdx.x, lane = tid & 63, wid = tid >> 6;
  int wm = (wid >> 1)*32, wn = (wid & 1)*64;
  int fr = lane & 15, qd = lane >> 4;
  int a_r = tid >> 2, a_c = (tid & 3)*8;
  int b_r = tid >> 1, b_c = (tid & 1)*16;
  const u16* Arow = pip + (((size_t)((b<<10) + p0 + a_r)) << 10) + a_c;
  const u16* Brow = snb + (((size_t)(b*512 + d0 + b_r)) << 10) + b_c;
  uint4 pa, pb0, pb1;
  auto issue = [&](int kk){
    pa = *(const uint4*)(Arow + kk);
    const uint4* bp = (const uint4*)(Brow + kk);
    pb0 = bp[0]; pb1 = bp[1];
  };
  f32x4 acc[2][4] = {};
  issue(0);
  for (int kk = 0; kk < 1024; kk += 32){
    *(uint4*)&As[a_r*40 + a_c] = pa;
    *(uint4*)&Bs[b_r*40 + b_c] = pb0;
    *(uint4*)&Bs[b_r*40 + b_c + 8] = pb1;
    __syncthreads();
    if (kk + 32 < 1024) issue(kk + 32);
    bf16x8 bfr[4];
    #pragma unroll
    for (int ni = 0; ni < 4; ++ni) bfr[ni] = ldfrag(&Bs[(wn + ni*16 + fr)*40 + qd*8]);
    #pragma unroll
    for (int mi = 0; mi < 2; ++mi){
      bf16x8 afr = ldfrag(&As[(wm + mi*16 + fr)*40 + qd*8]);
      #pragma unroll
      for (int ni = 0; ni < 4; ++ni) acc[mi][ni] = mfma16(afr, bfr[ni], acc[mi][ni]);
    }
    __syncthreads();
  }
  #pragma unroll
  for (int mi = 0; mi < 2; ++mi)
    #pragma unroll
    for (int ni = 0; ni < 4; ++ni)
      #pragma unroll
      for (int rg = 0; rg < 4; ++rg){
        int p = p0 + wm + mi*16 + qd*4 + rg;
        int d = d0 + wn + ni*16 + fr;
        float vout = acc[mi][ni][rg];
        size_t ro = (size_t)((b<<10) + p);
        tn[ro*512 + d] = vout;
        tcp[((size_t)(d>>5)*4096 + ro)*32 + (d&31)] = f2bf(vout);
      }
}

// ---------------- implicit-GEMM 3x3 conv: packed activations, frag-order weights
template<int CI, int CO, int KSPLIT, int MODE>
__global__ __launch_bounds__(256) void conv_k(const u16* __restrict__ inp, const u16* __restrict__ wpk,
        const float* __restrict__ bias, float* __restrict__ fout, u16* __restrict__ bout,
        const u16* __restrict__ tcp, const float* __restrict__ cnm, const float* __restrict__ cnis,
        const float* __restrict__ tn){
  constexpr int NCK_TOT = CI/32, NCK = NCK_TOT/KSPLIT;
  __shared__ __align__(16) u16 As[128*40];
  int b = blockIdx.z & 3, ks = blockIdx.z >> 2;
  int c0 = blockIdx.y*64;
  int r0 = blockIdx.x*2;
  int tid = threadIdx.x, lane = tid & 63, wid = tid >> 6;
  int wm = (wid >> 1)*32, wn = (wid & 1)*32;
  int fr = lane & 15, qd = lane >> 4;
  int ck0 = ks*NCK;
  int hrow = tid >> 1;
  int ah = (tid & 1)*16;
  int gy = r0 - 1 + (hrow >> 5);
  bool a_ok = ((unsigned)gy < 32u);
  size_t arow = (size_t)(b<<10) + (r0-1)*32 + hrow;
  uint4 pa0 = {0,0,0,0}, pa1 = {0,0,0,0};
  auto issueA = [&](int ck){
    if (a_ok){
      const uint4* s = (const uint4*)(inp + ((size_t)(ck0+ck)*4096 + arow)*32 + ah);
      pa0 = s[0]; pa1 = s[1];
    }
  };
  int g0 = (c0 + wn) >> 4;
  const u16* wb0 = wpk + ((size_t)(g0    )*NCK_TOT + ck0)*9*512 + lane*8;
  const u16* wb1 = wpk + ((size_t)(g0 + 1)*NCK_TOT + ck0)*9*512 + lane*8;

  f32x4 acc[2][2] = {};
  issueA(0);
  for (int ck = 0; ck < NCK; ++ck){
    *(uint4*)&As[hrow*40 + ah]     = pa0;
    *(uint4*)&As[hrow*40 + ah + 8] = pa1;
    __syncthreads();
    if (ck + 1 < NCK) issueA(ck + 1);
    #pragma unroll
    for (int tap = 0; tap < 9; ++tap){
      const int dy = tap/3 - 1, dx = tap%3 - 1;
      bf16x8 bf0 = ldfrag(wb0 + (size_t)(ck*9 + tap)*512);
      bf16x8 bf1 = ldfrag(wb1 + (size_t)(ck*9 + tap)*512);
      #pragma unroll
      for (int mi = 0; mi < 2; ++mi){
        int p0w = wm + mi*16;
        int pcol = (p0w & 31) + fr + dx;
        int lr = (p0w >> 5) + dy + 1;
        bool okc = (unsigned)pcol < 32u;
        bf16x8 af = ldfrag(&As[(lr*32 + (okc ? pcol : 0))*40 + qd*8]);
        if (!okc) af = bf16x8(0);
        acc[mi][0] = mfma16(af, bf0, acc[mi][0]);
        acc[mi][1] = mfma16(af, bf1, acc[mi][1]);
      }
    }
    __syncthreads();
  }
  #pragma unroll
  for (int mi = 0; mi < 2; ++mi)
    #pragma unroll
    for (int ni = 0; ni < 2; ++ni)
      #pragma unroll
      for (int rg = 0; rg < 4; ++rg){
        int pp = blockIdx.x*64 + wm + mi*16 + qd*4 + rg;
        int cc = c0 + wn + ni*16 + fr;
        float v = acc[mi][ni][rg];
        size_t ro = (size_t)((b<<10) + pp);
        if (MODE == 0){
          fout[(size_t)ks*4096*CO + ro*CO + cc] = v;
        } else {
          float alpha = v + bias[cc];
          float cn = (bf2f(tcp[((size_t)(16 + (cc>>5))*4096 + ro)*32 + (cc&31)])
                      - cnm[(b<<9) + cc]) * cnis[(b<<9) + cc];
          bout[((size_t)(cc>>5)*4096 + ro)*32 + (cc&31)] = f2bf(alpha*cn + tn[ro*512 + cc]);
        }
      }
}

// ---------------- decoder conv (512 -> 3): VALU reduction over packed t2
__global__ __launch_bounds__(512) void dec_k(const u16* __restrict__ t2p, const u16* __restrict__ wdp,
                                             const float* __restrict__ db, float* __restrict__ out){
  __shared__ float wlds[3*4608];
  int tid = threadIdx.x;
  for (int k = tid; k < 3*4608; k += 512){
    int c = k / 4608, rem = k - c*4608;
    int tap = rem >> 9, ci = rem & 511;
    wlds[k] = bf2f(wdp[(size_t)(tap*16 + c)*512 + ci]);
  }
  __syncthreads();
  int b = blockIdx.x >> 5;
  int p = ((blockIdx.x & 31) << 5) + (tid >> 4);
  int sub = tid & 15;
  int py = p >> 5, px = p & 31;
  float a0 = 0.f, a1 = 0.f, a2 = 0.f;
  for (int tap = 0; tap < 9; ++tap){
    int sy = py + tap/3 - 1, sx = px + tap%3 - 1;
    if (((unsigned)sy < 32u) && ((unsigned)sx < 32u)){
      size_t row = (size_t)((b<<10) + (sy<<5) + sx);
      const float* w0 = wlds + tap*512;
      #pragma unroll
      for (int j = 0; j < 4; ++j){
        int ci0 = j*128 + sub*8;
        uint4 v = *(const uint4*)(t2p + ((size_t)(ci0>>5)*4096 + row)*32 + (ci0&31));
        u32 ww[4] = {v.x, v.y, v.z, v.w};
        #pragma unroll
        for (int e = 0; e < 8; ++e){
          float x = bf2f((u16)((e & 1) ? (ww[e>>1] >> 16) : (ww[e>>1] & 0xffffu)));
          a0 += x * w0[ci0 + e];
          a1 += x * w0[4608 + ci0 + e];
          a2 += x * w0[9216 + ci0 + e];
        }
      }
    }
  }
  #pragma unroll
  for (int m = 8; m >= 1; m >>= 1){
    a0 += __shfl_xor(a0, m, 64);
    a1 += __shfl_xor(a1, m, 64);
    a2 += __shfl_xor(a2, m, 64);
  }
  if (sub == 0){
    out[((size_t)(b*3 + 0) << 10) + p] = a0 + db[0];
    out[((size_t)(b*3 + 1) << 10) + p] = a1 + db[1];
    out[((size_t)(b*3 + 2) << 10) + p] = a2 + db[2];
  }
}

// ---------------- fused BN: stats + apply in ONE kernel (internal grid sync)
// 128 blocks x 256 thr, all co-resident (<= 256 CUs) -> counter sync safe;
// budget guarantees termination. Activations stay in registers (xv fully
// unrolled -> no scratch), eliminating the 8MB z re-read of the old 2-kernel
// scheme. x = relu(za+zb+bias); ap = bf16(x*sc + sh) in packed layout.
__global__ __launch_bounds__(256) void bn_k(const float* __restrict__ z, const float* __restrict__ bias,
                    float* __restrict__ sums, const float* __restrict__ gamma,
                    const float* __restrict__ beta, u16* __restrict__ ap,
                    u32* __restrict__ ctr){
  int c = threadIdx.x;
  int r0 = blockIdx.x*32;
  float bi = bias[c];
  float xv[32];
  float s = 0.f, q = 0.f;
  #pragma unroll
  for (int i = 0; i < 32; ++i){
    size_t ro = (size_t)(r0 + i)*256 + c;
    float x = fmaxf(z[ro] + z[(size_t)4096*256 + ro] + bi, 0.f);
    xv[i] = x; s += x; q += x*x;
  }
  atomicAdd(&sums[c], s);
  atomicAdd(&sums[256 + c], q);
  __syncthreads();                     // drains atomics (vmcnt 0 before barrier)
  if (c == 0){
    __hip_atomic_fetch_add(ctr, 1u, __ATOMIC_RELAXED, __HIP_MEMORY_SCOPE_AGENT);
    int budget = 1 << 21;
    while (ld_agent_u32(ctr) < 128u && --budget > 0) __builtin_amdgcn_s_sleep(1);
  }
  __syncthreads();
  float S = ld_agentf(&sums[c]), Q = ld_agentf(&sums[256 + c]);
  float mean = S * (1.f/4096.f);
  float var  = Q * (1.f/4096.f) - mean*mean;
  float sc = gamma[c] * rsqrtf(var + 1e-5f);
  float sh = beta[c] - mean*sc;
  u16* apc = ap + ((size_t)(c>>5)*4096)*32 + (c&31);
  #pragma unroll
  for (int i = 0; i < 32; ++i)
    apc[(size_t)(r0 + i)*32] = f2bf(xv[i]*sc + sh);
}

// ---------------- launch ----------------
extern "C" void kernel_launch(void* const* d_in, const int* in_sizes, int n_in,
                              void* d_out, int out_size, void* d_ws, size_t ws_size,
                              hipStream_t stream){
  const float* cf  = (const float*)d_in[0];
  const float* sf  = (const float*)d_in[1];
  const float* w1  = (const float*)d_in[2];
  const float* b1  = (const float*)d_in[3];
  const float* g1  = (const float*)d_in[4];
  const float* be1 = (const float*)d_in[5];
  const float* w2  = (const float*)d_in[6];
  const float* b2  = (const float*)d_in[7];
  const float* g2  = (const float*)d_in[8];
  const float* be2 = (const float*)d_in[9];
  const float* w3  = (const float*)d_in[10];
  const float* b3  = (const float*)d_in[11];
  const float* dw  = (const float*)d_in[12];
  const float* db  = (const float*)d_in[13];

  char* ws = (char*)d_ws;
  u16* G    = (u16*)(ws + OFF_G);
  u16* Gt   = (u16*)(ws + OFF_GT);
  float* U    = (float*)(ws + OFF_U);
  float* V    = (float*)(ws + OFF_V);
  u32* bar    = (u32*)(ws + OFF_BAR);
  u32* ctr    = (u32*)(ws + OFF_CTR);
  float* cnm  = (float*)(ws + OFF_CNM);
  float* cnis = (float*)(ws + OFF_CNIS);
  float* bns1 = (float*)(ws + OFF_BNS);
  float* bns2 = bns1 + 512;
  float* pnp  = (float*)(ws + OFF_PNP);
  u16* cfh = (u16*)(ws + OFF_CFH);
  u16* cfl = (u16*)(ws + OFF_CFL);
  u16* sfh = (u16*)(ws + OFF_SFH);
  u16* sfl = (u16*)(ws + OFF_SFL);
  u16* snb = (u16*)(ws + OFF_SNB);
  float* tn  = (float*)(ws + OFF_TN);
  u16* tcp = (u16*)(ws + OFF_TCP);
  u16* w1p = (u16*)(ws + OFF_W1P);
  u16* w2p = (u16*)(ws + OFF_W2P);
  u16* w3p = (u16*)(ws + OFF_W3P);
  u16* wdp = (u16*)(ws + OFF_WDP);
  u16* pip = (u16*)(ws + OFF_PIP);
  float* z1  = (float*)(ws + OFF_Z1);
  u16*   a1p = (u16*)(ws + OFF_A1P);
  float* z2  = (float*)(ws + OFF_Z2);
  u16*   a2p = (u16*)(ws + OFF_A2P);
  u16*   t2p = (u16*)(ws + OFF_T2P);

  // fused: stats + zeroing + weight pack (one launch)
  stats_k<<<3541, 256, 0, stream>>>(cf, sf, cnm, cnis, pnp, U, bns1, bar, ctr,
                                    w1, w2, w3, dw, w1p, w2p, w3p, wdp);
  tsplit_k<<<dim3(16, 8, 8), 256, 0, stream>>>(cf, sf, pnp, cfh, cfl, sfh, sfl, tcp, snb);

  cgemm_k<<<dim3(8, 8, 4), 256, 0, stream>>>(cfh, cfl, sfh, sfl, G, Gt);

  // Sinkhorn + pi (blocks 0-255) + conv1 ks=1 overlay on idle CUs (256-511)
  sink_k<<<512, 512, 0, stream>>>(G, Gt, U, V, bar, pip, tcp, w1p, z1);

  tgemm_k<<<dim3(16, 4, 4), 256, 0, stream>>>(pip, snb, tn, tcp);

  // conv1 ks=0 half (t channels) -- ks=1 done in sink overlay
  conv_k<1024, 256, 2, 0><<<dim3(16, 4, 4), 256, 0, stream>>>(
      tcp, w1p, nullptr, z1, nullptr, nullptr, nullptr, nullptr, nullptr);
  bn_k<<<128, 256, 0, stream>>>(z1, b1, bns1, g1, be1, a1p, ctr);

  conv_k<256, 256, 2, 0><<<dim3(16, 4, 8), 256, 0, stream>>>(
      a1p, w2p, nullptr, z2, nullptr, nullptr, nullptr, nullptr, nullptr);
  bn_k<<<128, 256, 0, stream>>>(z2, b2, bns2, g2, be2, a2p, ctr + 16);

  conv_k<256, 512, 1, 1><<<dim3(16, 8, 4), 256, 0, stream>>>(
      a2p, w3p, b3, nullptr, t2p, tcp, cnm, cnis, tn);

  dec_k<<<128, 512, 0, stream>>>(t2p, wdp, db, (float*)d_out);

  (void)in_sizes; (void)n_in; (void)out_size; (void)ws_size;
}